// Round 8
// baseline (272.734 us; speedup 1.0000x reference)
//
#include <hip/hip_runtime.h>

typedef unsigned short u16;
typedef __attribute__((ext_vector_type(8))) short bf16x8;
typedef __attribute__((ext_vector_type(4))) float f32x4;

__device__ __forceinline__ float bf2f(u16 u) {
  union { unsigned u; float f; } c; c.u = ((unsigned)u) << 16; return c.f;
}
__device__ __forceinline__ u16 f2bf(float f) {
  union { float f; unsigned u; } c; c.f = f;
  unsigned u = c.u;
  return (u16)((u + 0x7FFFu + ((u >> 16) & 1u)) >> 16);
}
// async global->LDS, 16B per lane; LDS dest = wave-uniform base + lane*16
__device__ __forceinline__ void gld16(const void* g, void* l) {
  __builtin_amdgcn_global_load_lds(
      (__attribute__((address_space(1))) void*)g,
      (__attribute__((address_space(3))) void*)l, 16, 0, 0);
}

#define BB 32      // batch
#define CC 256     // channels
#define NN 1024    // H*W

// ---------------- 0. convert weights/biases fp32 -> bf16 --------------------
__global__ __launch_bounds__(256) void convert_w_kernel(
    const float* __restrict__ Wk, const float* __restrict__ bk,
    const float* __restrict__ Wp, const float* __restrict__ bp,
    u16* __restrict__ Wkb, u16* __restrict__ bkb,
    u16* __restrict__ Wpb, u16* __restrict__ bpb)
{
  int b = blockIdx.x, t = threadIdx.x;
  const float* src; u16* dst; int idx, n;
  if (b < 768)       { src = Wk; dst = Wkb; idx = b * 256 + t;        n = 196608; }
  else if (b < 771)  { src = bk; dst = bkb; idx = (b - 768) * 256 + t; n = 768;   }
  else if (b < 1027) { src = Wp; dst = Wpb; idx = (b - 771) * 256 + t; n = 65536; }
  else               { src = bp; dst = bpb; idx = t;                  n = 256;    }
  if (idx < n) dst[idx] = f2bf(src[idx]);
}

// ---------------- 1. BatchNorm stats ----------------------------------------
__global__ __launch_bounds__(256) void bn_stats_kernel(
    const float* __restrict__ x, const float* __restrict__ gamma,
    const float* __restrict__ beta, float* __restrict__ scl, float* __restrict__ sft)
{
  int c = blockIdx.x;
  int tid = threadIdx.x;
  float s = 0.f, q = 0.f;
  for (int g = tid; g < 8192; g += 256) {
    int b = g >> 8;
    int n = (g & 255) * 4;
    float4 v = *reinterpret_cast<const float4*>(x + (((size_t)(b * CC + c)) << 10) + n);
    s += v.x + v.y + v.z + v.w;
    q += v.x * v.x + v.y * v.y + v.z * v.z + v.w * v.w;
  }
  __shared__ float rs[256], rq[256];
  rs[tid] = s; rq[tid] = q;
  __syncthreads();
  for (int off = 128; off > 0; off >>= 1) {
    if (tid < off) { rs[tid] += rs[tid + off]; rq[tid] += rq[tid + off]; }
    __syncthreads();
  }
  if (tid == 0) {
    float mean = rs[0] * (1.f / 32768.f);
    float var  = rq[0] * (1.f / 32768.f) - mean * mean;
    float rstd = rsqrtf(var + 1e-5f);
    float g = gamma[c] * rstd;
    scl[c] = g;
    sft[c] = beta[c] - mean * g;
  }
}

// ---------------- 2. normalize + transpose [B,C,N] -> t[B,N,C] (bf16) -------
__global__ __launch_bounds__(256) void norm_transpose_kernel(
    const float* __restrict__ x, const float* __restrict__ scl,
    const float* __restrict__ sft, u16* __restrict__ t)
{
  __shared__ float tile[64][65];
  int b = blockIdx.z, n0 = blockIdx.x * 64, c0 = blockIdx.y * 64;
  int tid = threadIdx.x;
  int hi = tid >> 4, lo4 = (tid & 15) * 4;
  #pragma unroll
  for (int r = 0; r < 4; ++r) {
    int cl = r * 16 + hi;
    int c = c0 + cl;
    float4 v = *reinterpret_cast<const float4*>(
        x + (((size_t)(b * CC + c)) << 10) + n0 + lo4);
    float sc = scl[c], sh = sft[c];
    tile[cl][lo4 + 0] = v.x * sc + sh;
    tile[cl][lo4 + 1] = v.y * sc + sh;
    tile[cl][lo4 + 2] = v.z * sc + sh;
    tile[cl][lo4 + 3] = v.w * sc + sh;
  }
  __syncthreads();
  #pragma unroll
  for (int r = 0; r < 4; ++r) {
    int nl = r * 16 + hi;
    ushort4 o;
    o.x = f2bf(tile[lo4 + 0][nl]);
    o.y = f2bf(tile[lo4 + 1][nl]);
    o.z = f2bf(tile[lo4 + 2][nl]);
    o.w = f2bf(tile[lo4 + 3][nl]);
    *reinterpret_cast<ushort4*>(t + ((size_t)(b * NN + n0 + nl)) * CC + c0 + lo4) = o;
  }
}

// ---------------- 3. NT bf16 GEMM (R6 structure) ----------------------------
// mode 0: plain bf16 store; mode 1: transposed store vt; mode 2: proj+residual fp32
__global__ __launch_bounds__(256) void gemm_nt_kernel(
    const u16* __restrict__ A, int lda, size_t sA,
    const u16* __restrict__ B, int ldb, size_t sB,
    u16* __restrict__ C, int ldc, size_t sC,
    int K, const u16* __restrict__ bias, float scale, int mode,
    const float* __restrict__ xres, float* __restrict__ outf)
{
  __shared__ u16 As[128 * 32];   // unpadded: global_load_lds lane-contiguous
  __shared__ u16 Bs[128 * 32];
  int tid = threadIdx.x;
  int m0 = blockIdx.x * 128, n0 = blockIdx.y * 128;
  const u16* Ab = A + (size_t)blockIdx.z * sA;
  const u16* Bb = B + (size_t)blockIdx.z * sB;
  u16* Cb = C + (size_t)blockIdx.z * sC;

  int lane = tid & 63, w = tid >> 6;
  int lq = lane & 15, quad = lane >> 4;
  int wm = (w >> 1) * 64, wn = (w & 1) * 64;
  int ar = lane >> 2, ac = (lane & 3) * 8;
  int rb = w * 32;

  f32x4 zero = {0.f, 0.f, 0.f, 0.f};
  f32x4 acc[4][4];
  #pragma unroll
  for (int i = 0; i < 4; ++i)
    #pragma unroll
    for (int j = 0; j < 4; ++j) acc[i][j] = zero;

  for (int k0 = 0; k0 < K; k0 += 32) {
    __syncthreads();
    gld16(Ab + (size_t)(m0 + rb +      ar) * lda + k0 + ac, &As[(rb     ) * 32]);
    gld16(Ab + (size_t)(m0 + rb + 16 + ar) * lda + k0 + ac, &As[(rb + 16) * 32]);
    gld16(Bb + (size_t)(n0 + rb +      ar) * ldb + k0 + ac, &Bs[(rb     ) * 32]);
    gld16(Bb + (size_t)(n0 + rb + 16 + ar) * ldb + k0 + ac, &Bs[(rb + 16) * 32]);
    __syncthreads();
    bf16x8 af[4], bfr[4];
    #pragma unroll
    for (int i = 0; i < 4; ++i) {
      af[i]  = *reinterpret_cast<const bf16x8*>(&As[(wm + i * 16 + lq) * 32 + quad * 8]);
      bfr[i] = *reinterpret_cast<const bf16x8*>(&Bs[(wn + i * 16 + lq) * 32 + quad * 8]);
    }
    #pragma unroll
    for (int i = 0; i < 4; ++i)
      #pragma unroll
      for (int j = 0; j < 4; ++j)
        acc[i][j] = __builtin_amdgcn_mfma_f32_16x16x32_bf16(af[i], bfr[j], acc[i][j], 0, 0, 0);
  }

  #pragma unroll
  for (int j = 0; j < 4; ++j) {
    int col = n0 + wn + j * 16 + lq;
    float bv = bias ? bf2f(bias[col]) : 0.f;
    #pragma unroll
    for (int i = 0; i < 4; ++i) {
      int rbase = m0 + wm + i * 16 + quad * 4;
      if (mode == 2) {
        int b = rbase >> 10, n = rbase & 1023;
        size_t idx = (((size_t)(b * CC + col)) << 10) + n;
        float4 xv = *reinterpret_cast<const float4*>(xres + idx);
        float4 o;
        o.x = acc[i][j][0] * scale + bv + xv.x;
        o.y = acc[i][j][1] * scale + bv + xv.y;
        o.z = acc[i][j][2] * scale + bv + xv.z;
        o.w = acc[i][j][3] * scale + bv + xv.w;
        *reinterpret_cast<float4*>(outf + idx) = o;
      } else if (mode == 1) {
        int b = rbase >> 10, n = rbase & 1023;
        ushort4 o;
        o.x = f2bf(acc[i][j][0] * scale + bv);
        o.y = f2bf(acc[i][j][1] * scale + bv);
        o.z = f2bf(acc[i][j][2] * scale + bv);
        o.w = f2bf(acc[i][j][3] * scale + bv);
        *reinterpret_cast<ushort4*>(&Cb[(size_t)b * 262144 + (size_t)col * 1024 + n]) = o;
      } else {
        #pragma unroll
        for (int r = 0; r < 4; ++r)
          Cb[(size_t)(rbase + r) * ldc + col] = f2bf(acc[i][j][r] * scale + bv);
      }
    }
  }
}

// ---------------- 4. fused flash attention: O = softmax(QK^T/16) V ----------
// Grid (8 qtiles, 32 batches), 256 thr. qk [32768,512] (Q cols 0-255, K 256-511),
// vt [32,256,1024], o [32768,256] bf16. No max-subtraction (|s|<~7, exp safe);
// rowsum accumulated in LDS, applied at the end (linear, commutes past PV).
__global__ __launch_bounds__(256, 2) void flash_kernel(
    const u16* __restrict__ qk, const u16* __restrict__ vt, u16* __restrict__ o)
{
  // Qs: 8 chunks [128][32] = 64 KB (persistent)
  // KV: Ks 8 chunks [64][32] (16384 u16) | Vs 2 chunks [256][32] (16384 u16)
  //     | Ps 2 chunks [128][34] padded (8704 u16)   => 41472 u16 = 81 KB
  // Os epilogue [128][264] (33792 u16) aliases KV.
  __shared__ u16 Qs[32768];
  __shared__ u16 KV[41472];
  __shared__ float rowsumL[128];
  const int VS0 = 16384, PS0 = 32768;

  int tid = threadIdx.x;
  int lane = tid & 63, w = tid >> 6;
  int lq = lane & 15, quad = lane >> 4;
  int h = w & 1, v2 = w >> 1;          // q-half, kv/c-half of this wave
  int ar = lane >> 2, ac = (lane & 3) * 8;
  int b = blockIdx.y, q0 = blockIdx.x * 128;
  const u16* qb = qk + (size_t)b * 1024 * 512;
  const u16* vb = vt + (size_t)b * 256 * 1024;

  if (tid < 128) rowsumL[tid] = 0.f;

  // stage Q tile once: chunk kc, wave stages rows [32w, 32w+32)
  #pragma unroll
  for (int kc = 0; kc < 8; ++kc) {
    u16* dst = &Qs[kc * 4096 + (w * 32) * 32];
    gld16(qb + (size_t)(q0 + w * 32 +      ar) * 512 + kc * 32 + ac, dst);
    gld16(qb + (size_t)(q0 + w * 32 + 16 + ar) * 512 + kc * 32 + ac, dst + 512);
  }

  f32x4 zero = {0.f, 0.f, 0.f, 0.f};
  f32x4 accO[4][8];
  #pragma unroll
  for (int i = 0; i < 4; ++i)
    #pragma unroll
    for (int j = 0; j < 8; ++j) accO[i][j] = zero;

  for (int t = 0; t < 16; ++t) {       // kv tiles of 64
    int kv0 = t * 64;
    __syncthreads();                   // prev PV reads done; Ks/Vs free (also covers Q stage @t=0)
    // stage Ks: wave w stages chunks 2w, 2w+1 (each [64][32], 4 calls)
    #pragma unroll
    for (int cc = 0; cc < 2; ++cc) {
      int kc = 2 * w + cc;
      u16* dst = &KV[kc * 2048];
      #pragma unroll
      for (int rr = 0; rr < 4; ++rr)
        gld16(qb + (size_t)(kv0 + rr * 16 + ar) * 512 + 256 + kc * 32 + ac, dst + rr * 512);
    }
    // stage Vs: chunks ks=0,1 ([256][32]); wave w stages rows [64w, 64w+64)
    #pragma unroll
    for (int ks = 0; ks < 2; ++ks) {
      u16* dst = &KV[VS0 + ks * 8192 + (w * 64) * 32];
      #pragma unroll
      for (int rr = 0; rr < 4; ++rr)
        gld16(vb + (size_t)(w * 64 + rr * 16 + ar) * 1024 + kv0 + ks * 32 + ac, dst + rr * 512);
    }
    __syncthreads();
    // S phase: wave computes q rows [64h,+64), kv cols [32*v2,+32)
    f32x4 accS[4][2];
    #pragma unroll
    for (int i = 0; i < 4; ++i) { accS[i][0] = zero; accS[i][1] = zero; }
    #pragma unroll
    for (int kc = 0; kc < 8; ++kc) {
      bf16x8 af[4], bfr[2];
      #pragma unroll
      for (int i = 0; i < 4; ++i)
        af[i] = *reinterpret_cast<const bf16x8*>(&Qs[kc * 4096 + (64 * h + 16 * i + lq) * 32 + quad * 8]);
      #pragma unroll
      for (int j = 0; j < 2; ++j)
        bfr[j] = *reinterpret_cast<const bf16x8*>(&KV[kc * 2048 + (32 * v2 + 16 * j + lq) * 32 + quad * 8]);
      #pragma unroll
      for (int i = 0; i < 4; ++i)
        #pragma unroll
        for (int j = 0; j < 2; ++j)
          accS[i][j] = __builtin_amdgcn_mfma_f32_16x16x32_bf16(af[i], bfr[j], accS[i][j], 0, 0, 0);
    }
    // exp -> Ps (chunk v2, padded stride 34) + rowsum partials
    #pragma unroll
    for (int i = 0; i < 4; ++i) {
      #pragma unroll
      for (int r = 0; r < 4; ++r) {
        int row = 64 * h + 16 * i + 4 * quad + r;
        float part = 0.f;
        #pragma unroll
        for (int j = 0; j < 2; ++j) {
          u16 pb = f2bf(__expf(accS[i][j][r] * 0.0625f));
          KV[PS0 + v2 * 4352 + row * 34 + 16 * j + lq] = pb;
          part += bf2f(pb);
        }
        part += __shfl_xor(part, 1, 64);
        part += __shfl_xor(part, 2, 64);
        part += __shfl_xor(part, 4, 64);
        part += __shfl_xor(part, 8, 64);
        if (lq == 0) atomicAdd(&rowsumL[row], part);
      }
    }
    __syncthreads();                   // Ps visible to all waves
    // PV phase: wave: q rows [64h,+64), c cols [128*v2,+128), k = 64 kv
    #pragma unroll
    for (int ks = 0; ks < 2; ++ks) {
      bf16x8 pf[4], vf[8];
      #pragma unroll
      for (int i = 0; i < 4; ++i)
        pf[i] = *reinterpret_cast<const bf16x8*>(&KV[PS0 + ks * 4352 + (64 * h + 16 * i + lq) * 34 + quad * 8]);
      #pragma unroll
      for (int j = 0; j < 8; ++j)
        vf[j] = *reinterpret_cast<const bf16x8*>(&KV[VS0 + ks * 8192 + (128 * v2 + 16 * j + lq) * 32 + quad * 8]);
      #pragma unroll
      for (int i = 0; i < 4; ++i)
        #pragma unroll
        for (int j = 0; j < 8; ++j)
          accO[i][j] = __builtin_amdgcn_mfma_f32_16x16x32_bf16(pf[i], vf[j], accO[i][j], 0, 0, 0);
    }
  }
  __syncthreads();
  // epilogue: O /= rowsum, bf16 via LDS (aliases KV), coalesced store
  u16* Os = KV;                        // [128][264]
  #pragma unroll
  for (int i = 0; i < 4; ++i) {
    #pragma unroll
    for (int r = 0; r < 4; ++r) {
      int row = 64 * h + 16 * i + 4 * quad + r;
      float linv = 1.f / rowsumL[row];
      #pragma unroll
      for (int j = 0; j < 8; ++j)
        Os[row * 264 + 128 * v2 + 16 * j + lq] = f2bf(accO[i][j][r] * linv);
    }
  }
  __syncthreads();
  #pragma unroll
  for (int p = 0; p < 16; ++p) {
    int row = p * 8 + (tid >> 5), col = (tid & 31) * 8;
    bf16x8 vv = *reinterpret_cast<const bf16x8*>(&Os[row * 264 + col]);
    *reinterpret_cast<bf16x8*>(&o[((size_t)(b * 1024 + q0 + row)) * 256 + col]) = vv;
  }
}

extern "C" void kernel_launch(void* const* d_in, const int* in_sizes, int n_in,
                              void* d_out, int out_size, void* d_ws, size_t ws_size,
                              hipStream_t stream) {
  const float* x     = (const float*)d_in[0];
  const float* gamma = (const float*)d_in[1];
  const float* beta  = (const float*)d_in[2];
  const float* Wkqv  = (const float*)d_in[3];
  const float* bkqv  = (const float*)d_in[4];
  const float* Wproj = (const float*)d_in[5];
  const float* bproj = (const float*)d_in[6];
  float* out = (float*)d_out;          // fp32 [32,256,32,32]

  // ---- workspace layout (~65 MB) ----
  char* ws = (char*)d_ws;
  float* scl = (float*)ws;                      // 256 f32
  float* sft = (float*)(ws + 1024);             // 256 f32
  u16* Wkb = (u16*)(ws + 4096);                 // 196608 bf16
  u16* bkb = Wkb + 196608;
  u16* Wpb = bkb + 768;
  u16* bpb = Wpb + 65536;
  u16* qk   = (u16*)(ws + 1048576);             // [32768,512] bf16 = 32 MB
  u16* vt   = qk + (size_t)32768 * 512;         // [32,256,1024] bf16 = 16 MB
  u16* o_pv = vt + (size_t)32 * 256 * 1024;     // [32768,256] bf16 = 16 MB
  u16* t = (u16*)d_out;   // bf16 scratch in d_out, dead before mode-2 writes

  // 0. weight conversion
  convert_w_kernel<<<dim3(1028), dim3(256), 0, stream>>>(
      Wkqv, bkqv, Wproj, bproj, Wkb, bkb, Wpb, bpb);
  // 1. BN stats
  bn_stats_kernel<<<dim3(256), dim3(256), 0, stream>>>(x, gamma, beta, scl, sft);
  // 2. normalize + transpose -> t [B,N,C]
  norm_transpose_kernel<<<dim3(16, 4, 32), dim3(256), 0, stream>>>(x, scl, sft, t);
  // 3a. qk = t @ Wkqv[0:512]^T + b[0:512]
  gemm_nt_kernel<<<dim3(256, 4, 1), dim3(256), 0, stream>>>(
      t, 256, 0, Wkb, 256, 0, qk, 512, 0, 256, bkb, 1.0f, 0, nullptr, nullptr);
  // 3b. vt[b,c,n] = (t @ Wkqv[512:768]^T + b[512:768])^T
  gemm_nt_kernel<<<dim3(256, 2, 1), dim3(256), 0, stream>>>(
      t, 256, 0, Wkb + 512 * 256, 256, 0, vt, 0, 0, 256, bkb + 512, 1.0f, 1,
      nullptr, nullptr);
  // 4. fused attention: o_pv = softmax(QK^T/16) V
  flash_kernel<<<dim3(8, 32), dim3(256), 0, stream>>>(qk, vt, o_pv);
  // 5. fused proj+residual: out[b,c,n] = (o_pv @ Wproj^T + bproj)[n,c] + x[b,c,n]
  gemm_nt_kernel<<<dim3(256, 2, 1), dim3(256), 0, stream>>>(
      o_pv, 256, 0, Wpb, 256, 0, nullptr, 0, 0, 256, bpb, 1.0f, 2, x, out);
}

// Round 9
// 257.028 us; speedup vs baseline: 1.0611x; 1.0611x over previous
//
#include <hip/hip_runtime.h>

typedef unsigned short u16;
typedef __attribute__((ext_vector_type(8))) short bf16x8;
typedef __attribute__((ext_vector_type(4))) float f32x4;

__device__ __forceinline__ float bf2f(u16 u) {
  union { unsigned u; float f; } c; c.u = ((unsigned)u) << 16; return c.f;
}
__device__ __forceinline__ u16 f2bf(float f) {
  union { float f; unsigned u; } c; c.f = f;
  unsigned u = c.u;
  return (u16)((u + 0x7FFFu + ((u >> 16) & 1u)) >> 16);
}
// async global->LDS, 16B per lane; LDS dest = wave-uniform base + lane*16
__device__ __forceinline__ void gld16(const void* g, void* l) {
  __builtin_amdgcn_global_load_lds(
      (__attribute__((address_space(1))) void*)g,
      (__attribute__((address_space(3))) void*)l, 16, 0, 0);
}

#define BB 32      // batch
#define CC 256     // channels
#define NN 1024    // H*W

// ---------------- 0. convert weights/biases fp32 -> bf16 --------------------
__global__ __launch_bounds__(256) void convert_w_kernel(
    const float* __restrict__ Wk, const float* __restrict__ bk,
    const float* __restrict__ Wp, const float* __restrict__ bp,
    u16* __restrict__ Wkb, u16* __restrict__ bkb,
    u16* __restrict__ Wpb, u16* __restrict__ bpb)
{
  int b = blockIdx.x, t = threadIdx.x;
  const float* src; u16* dst; int idx, n;
  if (b < 768)       { src = Wk; dst = Wkb; idx = b * 256 + t;        n = 196608; }
  else if (b < 771)  { src = bk; dst = bkb; idx = (b - 768) * 256 + t; n = 768;   }
  else if (b < 1027) { src = Wp; dst = Wpb; idx = (b - 771) * 256 + t; n = 65536; }
  else               { src = bp; dst = bpb; idx = t;                  n = 256;    }
  if (idx < n) dst[idx] = f2bf(src[idx]);
}

// ---------------- 1. BatchNorm stats ----------------------------------------
__global__ __launch_bounds__(256) void bn_stats_kernel(
    const float* __restrict__ x, const float* __restrict__ gamma,
    const float* __restrict__ beta, float* __restrict__ scl, float* __restrict__ sft)
{
  int c = blockIdx.x;
  int tid = threadIdx.x;
  float s = 0.f, q = 0.f;
  for (int g = tid; g < 8192; g += 256) {
    int b = g >> 8;
    int n = (g & 255) * 4;
    float4 v = *reinterpret_cast<const float4*>(x + (((size_t)(b * CC + c)) << 10) + n);
    s += v.x + v.y + v.z + v.w;
    q += v.x * v.x + v.y * v.y + v.z * v.z + v.w * v.w;
  }
  __shared__ float rs[256], rq[256];
  rs[tid] = s; rq[tid] = q;
  __syncthreads();
  for (int off = 128; off > 0; off >>= 1) {
    if (tid < off) { rs[tid] += rs[tid + off]; rq[tid] += rq[tid + off]; }
    __syncthreads();
  }
  if (tid == 0) {
    float mean = rs[0] * (1.f / 32768.f);
    float var  = rq[0] * (1.f / 32768.f) - mean * mean;
    float rstd = rsqrtf(var + 1e-5f);
    float g = gamma[c] * rstd;
    scl[c] = g;
    sft[c] = beta[c] - mean * g;
  }
}

// ---------------- 2. normalize + transpose [B,C,N] -> t[B,N,C] (bf16) -------
__global__ __launch_bounds__(256) void norm_transpose_kernel(
    const float* __restrict__ x, const float* __restrict__ scl,
    const float* __restrict__ sft, u16* __restrict__ t)
{
  __shared__ float tile[64][65];
  int b = blockIdx.z, n0 = blockIdx.x * 64, c0 = blockIdx.y * 64;
  int tid = threadIdx.x;
  int hi = tid >> 4, lo4 = (tid & 15) * 4;
  #pragma unroll
  for (int r = 0; r < 4; ++r) {
    int cl = r * 16 + hi;
    int c = c0 + cl;
    float4 v = *reinterpret_cast<const float4*>(
        x + (((size_t)(b * CC + c)) << 10) + n0 + lo4);
    float sc = scl[c], sh = sft[c];
    tile[cl][lo4 + 0] = v.x * sc + sh;
    tile[cl][lo4 + 1] = v.y * sc + sh;
    tile[cl][lo4 + 2] = v.z * sc + sh;
    tile[cl][lo4 + 3] = v.w * sc + sh;
  }
  __syncthreads();
  #pragma unroll
  for (int r = 0; r < 4; ++r) {
    int nl = r * 16 + hi;
    ushort4 o;
    o.x = f2bf(tile[lo4 + 0][nl]);
    o.y = f2bf(tile[lo4 + 1][nl]);
    o.z = f2bf(tile[lo4 + 2][nl]);
    o.w = f2bf(tile[lo4 + 3][nl]);
    *reinterpret_cast<ushort4*>(t + ((size_t)(b * NN + n0 + nl)) * CC + c0 + lo4) = o;
  }
}

// ---------------- 3. NT bf16 GEMM (R6 structure) ----------------------------
// mode 0: plain bf16 store; mode 1: transposed store vt; mode 2: proj+residual fp32
__global__ __launch_bounds__(256) void gemm_nt_kernel(
    const u16* __restrict__ A, int lda, size_t sA,
    const u16* __restrict__ B, int ldb, size_t sB,
    u16* __restrict__ C, int ldc, size_t sC,
    int K, const u16* __restrict__ bias, float scale, int mode,
    const float* __restrict__ xres, float* __restrict__ outf)
{
  __shared__ u16 As[128 * 32];   // unpadded: global_load_lds lane-contiguous
  __shared__ u16 Bs[128 * 32];
  int tid = threadIdx.x;
  int m0 = blockIdx.x * 128, n0 = blockIdx.y * 128;
  const u16* Ab = A + (size_t)blockIdx.z * sA;
  const u16* Bb = B + (size_t)blockIdx.z * sB;
  u16* Cb = C + (size_t)blockIdx.z * sC;

  int lane = tid & 63, w = tid >> 6;
  int lq = lane & 15, quad = lane >> 4;
  int wm = (w >> 1) * 64, wn = (w & 1) * 64;
  int ar = lane >> 2, ac = (lane & 3) * 8;
  int rb = w * 32;

  f32x4 zero = {0.f, 0.f, 0.f, 0.f};
  f32x4 acc[4][4];
  #pragma unroll
  for (int i = 0; i < 4; ++i)
    #pragma unroll
    for (int j = 0; j < 4; ++j) acc[i][j] = zero;

  for (int k0 = 0; k0 < K; k0 += 32) {
    __syncthreads();
    gld16(Ab + (size_t)(m0 + rb +      ar) * lda + k0 + ac, &As[(rb     ) * 32]);
    gld16(Ab + (size_t)(m0 + rb + 16 + ar) * lda + k0 + ac, &As[(rb + 16) * 32]);
    gld16(Bb + (size_t)(n0 + rb +      ar) * ldb + k0 + ac, &Bs[(rb     ) * 32]);
    gld16(Bb + (size_t)(n0 + rb + 16 + ar) * ldb + k0 + ac, &Bs[(rb + 16) * 32]);
    __syncthreads();
    bf16x8 af[4], bfr[4];
    #pragma unroll
    for (int i = 0; i < 4; ++i) {
      af[i]  = *reinterpret_cast<const bf16x8*>(&As[(wm + i * 16 + lq) * 32 + quad * 8]);
      bfr[i] = *reinterpret_cast<const bf16x8*>(&Bs[(wn + i * 16 + lq) * 32 + quad * 8]);
    }
    #pragma unroll
    for (int i = 0; i < 4; ++i)
      #pragma unroll
      for (int j = 0; j < 4; ++j)
        acc[i][j] = __builtin_amdgcn_mfma_f32_16x16x32_bf16(af[i], bfr[j], acc[i][j], 0, 0, 0);
  }

  #pragma unroll
  for (int j = 0; j < 4; ++j) {
    int col = n0 + wn + j * 16 + lq;
    float bv = bias ? bf2f(bias[col]) : 0.f;
    #pragma unroll
    for (int i = 0; i < 4; ++i) {
      int rbase = m0 + wm + i * 16 + quad * 4;
      if (mode == 2) {
        int b = rbase >> 10, n = rbase & 1023;
        size_t idx = (((size_t)(b * CC + col)) << 10) + n;
        float4 xv = *reinterpret_cast<const float4*>(xres + idx);
        float4 o;
        o.x = acc[i][j][0] * scale + bv + xv.x;
        o.y = acc[i][j][1] * scale + bv + xv.y;
        o.z = acc[i][j][2] * scale + bv + xv.z;
        o.w = acc[i][j][3] * scale + bv + xv.w;
        *reinterpret_cast<float4*>(outf + idx) = o;
      } else if (mode == 1) {
        int b = rbase >> 10, n = rbase & 1023;
        ushort4 o;
        o.x = f2bf(acc[i][j][0] * scale + bv);
        o.y = f2bf(acc[i][j][1] * scale + bv);
        o.z = f2bf(acc[i][j][2] * scale + bv);
        o.w = f2bf(acc[i][j][3] * scale + bv);
        *reinterpret_cast<ushort4*>(&Cb[(size_t)b * 262144 + (size_t)col * 1024 + n]) = o;
      } else {
        #pragma unroll
        for (int r = 0; r < 4; ++r)
          Cb[(size_t)(rbase + r) * ldc + col] = f2bf(acc[i][j][r] * scale + bv);
      }
    }
  }
}

// ---------------- 4. flash v2: O = softmax(QK^T/16) V, occupancy-first ------
// Grid (32 batches, 16 qtiles) -> same-batch blocks land on same XCD (%8).
// q-tile 64 rows, kv-tile 64. LDS 74.25 KB -> 2 blocks/CU.
// Qs [8 chunks][64][32] persistent; Ks same per tile; P [2 chunks][64][40];
// V read global->VGPR (each element once per block, L2-served).
__global__ __launch_bounds__(256, 2) void flash_kernel(
    const u16* __restrict__ qk, const u16* __restrict__ vt, u16* __restrict__ o)
{
  __shared__ u16 smem[37888];          // Qs@0 (16384), Ks@16384 (16384), Ps@32768 (5120)
  __shared__ float rowsumL[64];
  const int KS0 = 16384, PS0 = 32768;

  int tid = threadIdx.x;
  int lane = tid & 63, w = tid >> 6;
  int lq = lane & 15, quad = lane >> 4;
  int ar = lane >> 2, ac = (lane & 3) * 8;
  int b = blockIdx.x, q0 = blockIdx.y * 64;
  const u16* qb = qk + (size_t)b * 1024 * 512;
  const u16* vb = vt + (size_t)b * 256 * 1024;

  if (tid < 64) rowsumL[tid] = 0.f;

  // stage Q tile once: wave w stages chunks 2w, 2w+1 (each [64][32] = 4 gld16)
  #pragma unroll
  for (int cc = 0; cc < 2; ++cc) {
    int kc = 2 * w + cc;
    #pragma unroll
    for (int rr = 0; rr < 4; ++rr)
      gld16(qb + (size_t)(q0 + rr * 16 + ar) * 512 + kc * 32 + ac,
            &smem[kc * 2048 + rr * 512]);
  }

  f32x4 zero = {0.f, 0.f, 0.f, 0.f};
  f32x4 accO[4][4];
  #pragma unroll
  for (int i = 0; i < 4; ++i)
    #pragma unroll
    for (int j = 0; j < 4; ++j) accO[i][j] = zero;

  for (int t = 0; t < 16; ++t) {       // kv tiles of 64
    int kv0 = t * 64;
    __syncthreads();                   // prev tile's PV reads done; Ks free (covers Q @t=0)
    // stage Ks (K rows kv0..kv0+64, cols 256..512 of qk)
    #pragma unroll
    for (int cc = 0; cc < 2; ++cc) {
      int kc = 2 * w + cc;
      #pragma unroll
      for (int rr = 0; rr < 4; ++rr)
        gld16(qb + (size_t)(kv0 + rr * 16 + ar) * 512 + 256 + kc * 32 + ac,
              &smem[KS0 + kc * 2048 + rr * 512]);
    }
    // V fragments direct to regs: wave's c cols [64w, 64w+64)
    bf16x8 vf[2][4];
    #pragma unroll
    for (int ks = 0; ks < 2; ++ks)
      #pragma unroll
      for (int j = 0; j < 4; ++j)
        vf[ks][j] = *reinterpret_cast<const bf16x8*>(
            vb + (size_t)(64 * w + 16 * j + lq) * 1024 + kv0 + ks * 32 + quad * 8);
    __syncthreads();
    // S phase: wave computes kv cols [16w, 16w+16) for all 64 q rows
    f32x4 accS[4];
    #pragma unroll
    for (int i = 0; i < 4; ++i) accS[i] = zero;
    #pragma unroll
    for (int kc = 0; kc < 8; ++kc) {
      bf16x8 bfr = *reinterpret_cast<const bf16x8*>(
          &smem[KS0 + kc * 2048 + (16 * w + lq) * 32 + quad * 8]);
      #pragma unroll
      for (int i = 0; i < 4; ++i) {
        bf16x8 af = *reinterpret_cast<const bf16x8*>(
            &smem[kc * 2048 + (16 * i + lq) * 32 + quad * 8]);
        accS[i] = __builtin_amdgcn_mfma_f32_16x16x32_bf16(af, bfr, accS[i], 0, 0, 0);
      }
    }
    // exp -> Ps (chunk w>>1, stride 40) + LDS rowsum partials
    int pchunk = w >> 1, pcol = 16 * (w & 1) + lq;
    #pragma unroll
    for (int i = 0; i < 4; ++i) {
      #pragma unroll
      for (int r = 0; r < 4; ++r) {
        int row = 16 * i + 4 * quad + r;
        u16 pb = f2bf(__expf(accS[i][r] * 0.0625f));
        smem[PS0 + pchunk * 2560 + row * 40 + pcol] = pb;
        float part = bf2f(pb);
        part += __shfl_xor(part, 1, 64);
        part += __shfl_xor(part, 2, 64);
        part += __shfl_xor(part, 4, 64);
        part += __shfl_xor(part, 8, 64);
        if (lq == 0) atomicAdd(&rowsumL[row], part);
      }
    }
    __syncthreads();                   // Ps visible
    // PV: wave's c cols [64w,+64), K = 64 kv in 2 chunks
    #pragma unroll
    for (int ks = 0; ks < 2; ++ks) {
      bf16x8 pf[4];
      #pragma unroll
      for (int i = 0; i < 4; ++i)
        pf[i] = *reinterpret_cast<const bf16x8*>(
            &smem[PS0 + ks * 2560 + (16 * i + lq) * 40 + quad * 8]);
      #pragma unroll
      for (int i = 0; i < 4; ++i)
        #pragma unroll
        for (int j = 0; j < 4; ++j)
          accO[i][j] = __builtin_amdgcn_mfma_f32_16x16x32_bf16(pf[i], vf[ks][j], accO[i][j], 0, 0, 0);
    }
  }
  __syncthreads();
  // epilogue: O /= rowsum, via LDS [64][272] (aliases Qs+Ks), coalesced store
  #pragma unroll
  for (int i = 0; i < 4; ++i) {
    #pragma unroll
    for (int r = 0; r < 4; ++r) {
      int row = 16 * i + 4 * quad + r;
      float linv = 1.f / rowsumL[row];
      #pragma unroll
      for (int j = 0; j < 4; ++j)
        smem[row * 272 + 64 * w + 16 * j + lq] = f2bf(accO[i][j][r] * linv);
    }
  }
  __syncthreads();
  #pragma unroll
  for (int p = 0; p < 8; ++p) {
    int idx = p * 256 + tid;
    int row = idx >> 5, col = (idx & 31) * 8;
    bf16x8 vv = *reinterpret_cast<const bf16x8*>(&smem[row * 272 + col]);
    *reinterpret_cast<bf16x8*>(&o[((size_t)(b * 1024 + q0 + row)) * 256 + col]) = vv;
  }
}

extern "C" void kernel_launch(void* const* d_in, const int* in_sizes, int n_in,
                              void* d_out, int out_size, void* d_ws, size_t ws_size,
                              hipStream_t stream) {
  const float* x     = (const float*)d_in[0];
  const float* gamma = (const float*)d_in[1];
  const float* beta  = (const float*)d_in[2];
  const float* Wkqv  = (const float*)d_in[3];
  const float* bkqv  = (const float*)d_in[4];
  const float* Wproj = (const float*)d_in[5];
  const float* bproj = (const float*)d_in[6];
  float* out = (float*)d_out;          // fp32 [32,256,32,32]

  // ---- workspace layout (~65 MB) ----
  char* ws = (char*)d_ws;
  float* scl = (float*)ws;                      // 256 f32
  float* sft = (float*)(ws + 1024);             // 256 f32
  u16* Wkb = (u16*)(ws + 4096);                 // 196608 bf16
  u16* bkb = Wkb + 196608;
  u16* Wpb = bkb + 768;
  u16* bpb = Wpb + 65536;
  u16* qk   = (u16*)(ws + 1048576);             // [32768,512] bf16 = 32 MB
  u16* vt   = qk + (size_t)32768 * 512;         // [32,256,1024] bf16 = 16 MB
  u16* o_pv = vt + (size_t)32 * 256 * 1024;     // [32768,256] bf16 = 16 MB
  u16* t = (u16*)d_out;   // bf16 scratch in d_out, dead before mode-2 writes

  // 0. weight conversion
  convert_w_kernel<<<dim3(1028), dim3(256), 0, stream>>>(
      Wkqv, bkqv, Wproj, bproj, Wkb, bkb, Wpb, bpb);
  // 1. BN stats
  bn_stats_kernel<<<dim3(256), dim3(256), 0, stream>>>(x, gamma, beta, scl, sft);
  // 2. normalize + transpose -> t [B,N,C]
  norm_transpose_kernel<<<dim3(16, 4, 32), dim3(256), 0, stream>>>(x, scl, sft, t);
  // 3a. qk = t @ Wkqv[0:512]^T + b[0:512]
  gemm_nt_kernel<<<dim3(256, 4, 1), dim3(256), 0, stream>>>(
      t, 256, 0, Wkb, 256, 0, qk, 512, 0, 256, bkb, 1.0f, 0, nullptr, nullptr);
  // 3b. vt[b,c,n] = (t @ Wkqv[512:768]^T + b[512:768])^T
  gemm_nt_kernel<<<dim3(256, 2, 1), dim3(256), 0, stream>>>(
      t, 256, 0, Wkb + 512 * 256, 256, 0, vt, 0, 0, 256, bkb + 512, 1.0f, 1,
      nullptr, nullptr);
  // 4. fused attention: o_pv = softmax(QK^T/16) V
  flash_kernel<<<dim3(32, 16), dim3(256), 0, stream>>>(qk, vt, o_pv);
  // 5. fused proj+residual: out[b,c,n] = (o_pv @ Wproj^T + bproj)[n,c] + x[b,c,n]
  gemm_nt_kernel<<<dim3(256, 2, 1), dim3(256), 0, stream>>>(
      o_pv, 256, 0, Wpb, 256, 0, nullptr, 0, 0, 256, bpb, 1.0f, 2, x, out);
}